// Round 2
// baseline (1319.694 us; speedup 1.0000x reference)
//
#include <hip/hip_runtime.h>
#include <math.h>

#define FEAT 256
#define RANKK 16
#define SBLK 4096       // elements per selection block (256 threads x 16)
#define PRJ_NODES 16    // nodes per proj block

// ---------------- proj = x @ W^T  (double accumulation, f32 output) ----------------
__global__ __launch_bounds__(256) void proj_kernel(const float* __restrict__ x,
                            const float* __restrict__ Wm,
                            float* __restrict__ proj, int n_nodes) {
    __shared__ float Ws[RANKK][FEAT + 1];
    __shared__ float Xs[PRJ_NODES][FEAT + 1];
    const float4* x4 = (const float4*)x;
    const float4* w4 = (const float4*)Wm;
    // stage W (16x256) and 16 x-rows, vectorized + coalesced
    for (int t = threadIdx.x; t < RANKK * (FEAT / 4); t += 256) {
        int r = t >> 6, j4 = t & 63;
        float4 v = w4[t];
        Ws[r][j4 * 4 + 0] = v.x; Ws[r][j4 * 4 + 1] = v.y;
        Ws[r][j4 * 4 + 2] = v.z; Ws[r][j4 * 4 + 3] = v.w;
    }
    int nodeBase = blockIdx.x * PRJ_NODES;
    for (int t = threadIdx.x; t < PRJ_NODES * (FEAT / 4); t += 256) {
        int n = t >> 6, j4 = t & 63;
        int node = nodeBase + n;
        float4 v = make_float4(0.f, 0.f, 0.f, 0.f);
        if (node < n_nodes) v = x4[(size_t)node * (FEAT / 4) + j4];
        Xs[n][j4 * 4 + 0] = v.x; Xs[n][j4 * 4 + 1] = v.y;
        Xs[n][j4 * 4 + 2] = v.z; Xs[n][j4 * 4 + 3] = v.w;
    }
    __syncthreads();
    int n = threadIdx.x >> 4, r = threadIdx.x & 15;
    int node = nodeBase + n;
    if (node >= n_nodes) return;
    double acc = 0.0;
    #pragma unroll 8
    for (int j = 0; j < FEAT; ++j)
        acc += (double)Xs[n][j] * (double)Ws[r][j];
    proj[(size_t)node * RANKK + r] = (float)acc;
}

// ---------------- ef2[e] = ef[edge_ids[e]]  (kill double indirection) ----------------
__global__ void gather_ef(const float4* __restrict__ ef, const int* __restrict__ edge_ids,
                          float4* __restrict__ ef2, int nhe) {
    int t = blockIdx.x * blockDim.x + threadIdx.x;
    if (t >= nhe * 4) return;
    int e = t >> 2, c = t & 3;
    ef2[(size_t)e * 4 + c] = ef[(size_t)edge_ids[e] * 4 + c];
}

// ------------- scores + edge sums/counts + level-1 histogram (4-wide ILP) -------------
__global__ __launch_bounds__(256) void score_kernel(
        const float4* __restrict__ proj4, const float4* __restrict__ ef4,
        const int4* __restrict__ V4, const int4* __restrict__ E4,
        float* __restrict__ scores, float* __restrict__ e_ssum,
        unsigned* __restrict__ e_cnt, unsigned* __restrict__ hist1,
        int n4, int nnz) {
    __shared__ unsigned h[4096];
    for (int t = threadIdx.x; t < 4096; t += 256) h[t] = 0;
    __syncthreads();
    int stride = gridDim.x * 256;
    for (int i = blockIdx.x * 256 + threadIdx.x; i < n4; i += stride) {
        int4 v = V4[i];
        int4 e = E4[i];
        int va[4] = {v.x, v.y, v.z, v.w};
        int ea[4] = {e.x, e.y, e.z, e.w};
        float4 P[4][4], F[4][4];
        #pragma unroll
        for (int q = 0; q < 4; ++q) {
            #pragma unroll
            for (int c = 0; c < 4; ++c) {
                P[q][c] = proj4[(size_t)va[q] * 4 + c];
                F[q][c] = ef4[(size_t)ea[q] * 4 + c];
            }
        }
        float sf[4];
        #pragma unroll
        for (int q = 0; q < 4; ++q) {
            double acc = 0.0;
            #pragma unroll
            for (int c = 0; c < 4; ++c) {
                acc += (double)P[q][c].x * (double)F[q][c].x;
                acc += (double)P[q][c].y * (double)F[q][c].y;
                acc += (double)P[q][c].z * (double)F[q][c].z;
                acc += (double)P[q][c].w * (double)F[q][c].w;
            }
            double s = 1.0 / (1.0 + exp(-acc));
            sf[q] = (float)s;
        }
        float4 sv = make_float4(sf[0], sf[1], sf[2], sf[3]);
        ((float4*)scores)[i] = sv;
        #pragma unroll
        for (int q = 0; q < 4; ++q) {
            atomicAdd(&e_ssum[ea[q]], sf[q]);
            atomicAdd(&e_cnt[ea[q]], 1u);
            atomicAdd(&h[__float_as_uint(sf[q]) >> 20], 1u);
        }
    }
    // scalar tail (nnz not multiple of 4)
    for (int i = n4 * 4 + blockIdx.x * 256 + threadIdx.x; i < nnz; i += stride) {
        const float* pr = (const float*)proj4;
        const float* fr = (const float*)ef4;
        const int* Vi = (const int*)V4;
        const int* Ei = (const int*)E4;
        int v = Vi[i], e = Ei[i];
        double acc = 0.0;
        #pragma unroll
        for (int r = 0; r < RANKK; ++r)
            acc += (double)pr[(size_t)v * RANKK + r] * (double)fr[(size_t)e * RANKK + r];
        double s = 1.0 / (1.0 + exp(-acc));
        float sf = (float)s;
        scores[i] = sf;
        atomicAdd(&e_ssum[e], sf);
        atomicAdd(&e_cnt[e], 1u);
        atomicAdd(&h[__float_as_uint(sf) >> 20], 1u);
    }
    __syncthreads();
    for (int t = threadIdx.x; t < 4096; t += 256)
        if (h[t]) atomicAdd(&hist1[t], h[t]);
}

// ---------------- radix-select scan (single thread, tiny) ----------------
// sel[0]=k_rem, sel[1]=prefix bits, sel[2]=T (exact bits), sel[3]=m (ties to keep)
__global__ void scan_kernel(const unsigned* __restrict__ hist, int nbins,
                            unsigned* __restrict__ sel, const int* __restrict__ kptr, int level) {
    if (threadIdx.x != 0 || blockIdx.x != 0) return;
    unsigned krem = (level == 0) ? (unsigned)(*kptr) : sel[0];
    unsigned cum = 0;
    int b = nbins - 1;
    while (b > 0) {
        unsigned c = hist[b];
        if (cum + c >= krem) break;
        cum += c;
        --b;
    }
    unsigned newk = krem - cum;
    sel[0] = newk;
    if (level == 0) {
        sel[1] = ((unsigned)b) << 20;
    } else if (level == 1) {
        sel[1] |= ((unsigned)b) << 8;
    } else {
        unsigned T = sel[1] | (unsigned)b;
        sel[2] = T;
        sel[3] = newk;   // number of ==T elements to keep (lowest index first)
    }
}

// ------------- level-2 / level-3 histogram passes over scores -------------
__global__ void hist_pass(const float* __restrict__ scores, const unsigned* __restrict__ sel,
                          unsigned* __restrict__ hist, int nnz, int mode) {
    __shared__ unsigned h[4096];
    const int nb = (mode == 1) ? 4096 : 256;
    for (int t = threadIdx.x; t < nb; t += blockDim.x) h[t] = 0;
    __syncthreads();
    unsigned pref = sel[1];
    for (int i = blockIdx.x * blockDim.x + threadIdx.x; i < nnz; i += gridDim.x * blockDim.x) {
        unsigned bits = __float_as_uint(scores[i]);
        if (mode == 1) {
            if ((bits >> 20) == (pref >> 20)) atomicAdd(&h[(bits >> 8) & 0xFFF], 1u);
        } else {
            if ((bits >> 8) == (pref >> 8)) atomicAdd(&h[bits & 0xFF], 1u);
        }
    }
    __syncthreads();
    for (int t = threadIdx.x; t < nb; t += blockDim.x)
        if (h[t]) atomicAdd(&hist[t], h[t]);
}

// ------------- per-block count of elements exactly == T -------------
__global__ void eq_count(const float* __restrict__ scores, const unsigned* __restrict__ sel,
                         unsigned* __restrict__ blockCnt, int nnz) {
    __shared__ unsigned red[256];
    unsigned T = sel[2];
    int base = blockIdx.x * SBLK + threadIdx.x * 16;
    unsigned cnt = 0;
    #pragma unroll
    for (int s = 0; s < 16; ++s) {
        int i = base + s;
        if (i < nnz) cnt += (__float_as_uint(scores[i]) == T);
    }
    red[threadIdx.x] = cnt;
    __syncthreads();
    for (int off = 128; off > 0; off >>= 1) {
        if (threadIdx.x < off) red[threadIdx.x] += red[threadIdx.x + off];
        __syncthreads();
    }
    if (threadIdx.x == 0) blockCnt[blockIdx.x] = red[0];
}

// serial exclusive scan over block counts (~977 entries -> trivial)
__global__ void scan_blocks(unsigned* __restrict__ blockCnt, int nblocks) {
    if (threadIdx.x != 0 || blockIdx.x != 0) return;
    unsigned run = 0;
    for (int j = 0; j < nblocks; ++j) {
        unsigned c = blockCnt[j];
        blockCnt[j] = run;
        run += c;
    }
}

// ------------- write hard/soft + edge hard-sum, exact tie handling -------------
__global__ void write_hard(const float* __restrict__ scores, const unsigned* __restrict__ sel,
                           const unsigned* __restrict__ blockCnt,
                           float* __restrict__ hard, float* __restrict__ soft,
                           const int* __restrict__ E_idx, unsigned* __restrict__ e_hsum, int nnz) {
    __shared__ unsigned ps[256];
    unsigned T = sel[2];
    unsigned m = sel[3];
    int base = blockIdx.x * SBLK + threadIdx.x * 16;

    // pass 1: count my equals
    unsigned cnt = 0;
    #pragma unroll
    for (int s = 0; s < 16; ++s) {
        int i = base + s;
        if (i < nnz) cnt += (__float_as_uint(scores[i]) == T);
    }
    ps[threadIdx.x] = cnt;
    __syncthreads();
    // Hillis-Steele inclusive scan over 256 thread counts
    for (int off = 1; off < 256; off <<= 1) {
        unsigned v = 0;
        if (threadIdx.x >= (unsigned)off) v = ps[threadIdx.x - off];
        __syncthreads();
        ps[threadIdx.x] += v;
        __syncthreads();
    }
    unsigned running = blockCnt[blockIdx.x] + ps[threadIdx.x] - cnt;

    // pass 2: classify in index order
    #pragma unroll
    for (int s = 0; s < 16; ++s) {
        int i = base + s;
        if (i >= nnz) break;
        unsigned bits = __float_as_uint(scores[i]);
        bool keep;
        if (bits > T) {
            keep = true;
        } else if (bits == T) {
            keep = (running < m);
            ++running;
        } else {
            keep = false;
        }
        float hv = keep ? 1.0f : 0.0f;
        hard[i] = hv;
        soft[i] = hv;   // forward: soft == hard exactly
        if (keep) atomicAdd(&e_hsum[E_idx[i]], 1u);
    }
}

// ---------------- per-hyperedge finalize ----------------
__global__ void finalize_edges(const float* __restrict__ ssum, const unsigned* __restrict__ cnt,
                               const unsigned* __restrict__ hsum,
                               float* __restrict__ eprob, float* __restrict__ esoft,
                               float* __restrict__ ehard, int nhe) {
    int j = blockIdx.x * blockDim.x + threadIdx.x;
    if (j >= nhe) return;
    float c = fmaxf((float)cnt[j], 1.0f);
    eprob[j] = ssum[j] / c;
    esoft[j] = (float)hsum[j] / c;
    ehard[j] = (hsum[j] > 0) ? 1.0f : 0.0f;
}

extern "C" void kernel_launch(void* const* d_in, const int* in_sizes, int n_in,
                              void* d_out, int out_size, void* d_ws, size_t ws_size,
                              hipStream_t stream) {
    const float* x        = (const float*)d_in[0];
    const float* Wm       = (const float*)d_in[1];
    const float* ef       = (const float*)d_in[2];
    const int*   V_idx    = (const int*)d_in[3];
    const int*   E_idx    = (const int*)d_in[4];
    const int*   edge_ids = (const int*)d_in[5];
    const int*   kptr     = (const int*)d_in[6];

    const int nnz     = in_sizes[3];
    const int nhe     = in_sizes[5];
    const int n_nodes = in_sizes[0] / FEAT;

    float* out    = (float*)d_out;
    float* scores = out;
    float* soft   = out + (size_t)nnz;
    float* hard   = out + 2 * (size_t)nnz;
    float* eprob  = out + 3 * (size_t)nnz;
    float* esoft  = eprob + nhe;
    float* ehard  = esoft + nhe;

    const int nb4 = (nnz + SBLK - 1) / SBLK;

    // ---- workspace layout: aux zone always in d_ws ----
    char* w = (char*)d_ws;
    float*    e_ssum   = (float*)w;
    unsigned* e_cnt    = (unsigned*)(e_ssum + nhe);
    unsigned* e_hsum   = e_cnt + nhe;
    unsigned* hist1    = e_hsum + nhe;
    unsigned* hist2    = hist1 + 4096;
    unsigned* hist3    = hist2 + 4096;
    unsigned* blockCnt = hist3 + 256;
    unsigned* sel      = blockCnt + nb4;
    size_t auxBytes = (size_t)((char*)(sel + 8) - (char*)w);
    size_t auxAligned = (auxBytes + 255) & ~(size_t)255;

    // big zone: ef2 (nhe*16 f32) then proj (n_nodes*16 f32)
    size_t ef2Bytes  = (size_t)nhe * RANKK * sizeof(float);
    size_t projBytes = (size_t)n_nodes * RANKK * sizeof(float);
    float* ef2;
    float* proj;
    if (ws_size >= auxAligned + ef2Bytes + projBytes) {
        ef2  = (float*)(w + auxAligned);
        proj = (float*)(w + auxAligned + ef2Bytes);
    } else {
        // stage in the 'soft' output region (nnz*4 bytes >= ef2+proj);
        // consumed by score_kernel before write_hard overwrites soft.
        ef2  = soft;
        proj = soft + (size_t)nhe * RANKK;
    }

    hipMemsetAsync(w, 0, auxBytes, stream);

    gather_ef<<<(nhe * 4 + 255) / 256, 256, 0, stream>>>(
        (const float4*)ef, edge_ids, (float4*)ef2, nhe);
    proj_kernel<<<(n_nodes + PRJ_NODES - 1) / PRJ_NODES, 256, 0, stream>>>(
        x, Wm, proj, n_nodes);

    int n4 = nnz / 4;
    score_kernel<<<2048, 256, 0, stream>>>(
        (const float4*)proj, (const float4*)ef2,
        (const int4*)V_idx, (const int4*)E_idx,
        scores, e_ssum, e_cnt, hist1, n4, nnz);

    scan_kernel<<<1, 1, 0, stream>>>(hist1, 4096, sel, kptr, 0);
    hist_pass<<<2048, 256, 0, stream>>>(scores, sel, hist2, nnz, 1);
    scan_kernel<<<1, 1, 0, stream>>>(hist2, 4096, sel, kptr, 1);
    hist_pass<<<2048, 256, 0, stream>>>(scores, sel, hist3, nnz, 2);
    scan_kernel<<<1, 1, 0, stream>>>(hist3, 256, sel, kptr, 2);
    eq_count<<<nb4, 256, 0, stream>>>(scores, sel, blockCnt, nnz);
    scan_blocks<<<1, 1, 0, stream>>>(blockCnt, nb4);
    write_hard<<<nb4, 256, 0, stream>>>(scores, sel, blockCnt, hard, soft, E_idx, e_hsum, nnz);
    finalize_edges<<<(nhe + 255) / 256, 256, 0, stream>>>(e_ssum, e_cnt, e_hsum,
                                                          eprob, esoft, ehard, nhe);
}

// Round 3
// 668.011 us; speedup vs baseline: 1.9756x; 1.9756x over previous
//
#include <hip/hip_runtime.h>
#include <math.h>

#define FEAT 256
#define RANKK 16
#define PRJ_NODES 16
#define CAND_CAP 131072
#define TIE_CAP 2048

// ---------------- proj = x @ W^T  (double accumulation, f32 output) ----------------
__global__ __launch_bounds__(256) void proj_kernel(const float* __restrict__ x,
                            const float* __restrict__ Wm,
                            float* __restrict__ proj, int n_nodes) {
    __shared__ float Ws[RANKK][FEAT + 1];
    __shared__ float Xs[PRJ_NODES][FEAT + 1];
    const float4* x4 = (const float4*)x;
    const float4* w4 = (const float4*)Wm;
    for (int t = threadIdx.x; t < RANKK * (FEAT / 4); t += 256) {
        int r = t >> 6, j4 = t & 63;
        float4 v = w4[t];
        Ws[r][j4 * 4 + 0] = v.x; Ws[r][j4 * 4 + 1] = v.y;
        Ws[r][j4 * 4 + 2] = v.z; Ws[r][j4 * 4 + 3] = v.w;
    }
    int nodeBase = blockIdx.x * PRJ_NODES;
    for (int t = threadIdx.x; t < PRJ_NODES * (FEAT / 4); t += 256) {
        int n = t >> 6, j4 = t & 63;
        int node = nodeBase + n;
        float4 v = make_float4(0.f, 0.f, 0.f, 0.f);
        if (node < n_nodes) v = x4[(size_t)node * (FEAT / 4) + j4];
        Xs[n][j4 * 4 + 0] = v.x; Xs[n][j4 * 4 + 1] = v.y;
        Xs[n][j4 * 4 + 2] = v.z; Xs[n][j4 * 4 + 3] = v.w;
    }
    __syncthreads();
    int n = threadIdx.x >> 4, r = threadIdx.x & 15;
    int node = nodeBase + n;
    if (node >= n_nodes) return;
    double acc = 0.0;
    #pragma unroll 8
    for (int j = 0; j < FEAT; ++j)
        acc += (double)Xs[n][j] * (double)Ws[r][j];
    proj[(size_t)node * RANKK + r] = (float)acc;
}

// ---------------- ef2[e] = ef[edge_ids[e]] ----------------
__global__ void gather_ef(const float4* __restrict__ ef, const int* __restrict__ edge_ids,
                          float4* __restrict__ ef2, int nhe) {
    int t = blockIdx.x * blockDim.x + threadIdx.x;
    if (t >= nhe * 4) return;
    int e = t >> 2, c = t & 3;
    ef2[(size_t)e * 4 + c] = ef[(size_t)edge_ids[e] * 4 + c];
}

// ------------- lane-cooperative scores + edge sums + level-1 histogram -------------
// 4 lanes per incidence; 64 incidences per wave per batch.
__global__ __launch_bounds__(256) void score_kernel(
        const float4* __restrict__ proj4, const float4* __restrict__ ef4,
        const int* __restrict__ V_idx, const int* __restrict__ E_idx,
        float* __restrict__ scores, float* __restrict__ e_ssum,
        unsigned* __restrict__ e_cnt, unsigned* __restrict__ hist1, int nnz) {
    __shared__ unsigned h[4096];
    for (int t = threadIdx.x; t < 4096; t += 256) h[t] = 0;
    __syncthreads();
    const int lane = threadIdx.x & 63;
    const int wid  = (blockIdx.x * 256 + threadIdx.x) >> 6;
    const int nw   = (gridDim.x * 256) >> 6;
    const int sub  = lane >> 2;     // incidence slot in round (0..15)
    const int c    = lane & 3;      // quarter of rank-16 row
    const int nbatch = (nnz + 63) >> 6;
    for (int b = wid; b < nbatch; b += nw) {
        const int base = b << 6;
        int iv[4], ie[4];
        bool valid[4];
        #pragma unroll
        for (int s = 0; s < 4; ++s) {
            int i = base + s * 16 + sub;
            valid[s] = (i < nnz);
            int ii = valid[s] ? i : (nnz - 1);
            iv[s] = V_idx[ii];
            ie[s] = E_idx[ii];
        }
        float4 P[4], F[4];
        #pragma unroll
        for (int s = 0; s < 4; ++s) {
            P[s] = proj4[(size_t)iv[s] * 4 + c];
            F[s] = ef4[(size_t)ie[s] * 4 + c];
        }
        float sf[4];
        #pragma unroll
        for (int s = 0; s < 4; ++s) {
            double part = (double)P[s].x * (double)F[s].x
                        + (double)P[s].y * (double)F[s].y
                        + (double)P[s].z * (double)F[s].z
                        + (double)P[s].w * (double)F[s].w;
            part += __shfl_xor(part, 1, 64);
            part += __shfl_xor(part, 2, 64);
            double sd = 1.0 / (1.0 + exp(-part));
            sf[s] = (float)sd;
        }
        #pragma unroll
        for (int s = 0; s < 4; ++s) {
            if (c == 0 && valid[s]) {
                atomicAdd(&e_ssum[ie[s]], sf[s]);
                atomicAdd(&e_cnt[ie[s]], 1u);
                atomicAdd(&h[__float_as_uint(sf[s]) >> 20], 1u);
            }
        }
        // redistribute so lane j stores scores[base+j] (coalesced)
        int src = (lane & 15) * 4;
        float t0 = __shfl(sf[0], src, 64);
        float t1 = __shfl(sf[1], src, 64);
        float t2 = __shfl(sf[2], src, 64);
        float t3 = __shfl(sf[3], src, 64);
        int s = lane >> 4;
        float val = (s == 0) ? t0 : (s == 1) ? t1 : (s == 2) ? t2 : t3;
        int oi = base + lane;
        if (oi < nnz) scores[oi] = val;
    }
    __syncthreads();
    for (int t = threadIdx.x; t < 4096; t += 256)
        if (h[t]) atomicAdd(&hist1[t], h[t]);
}

// ------------- parallel level-1 suffix scan: pref bin + krem (1 block) -------------
__global__ void scan1_kernel(const unsigned* __restrict__ hist,
                             unsigned* __restrict__ sel, const int* __restrict__ kptr) {
    __shared__ unsigned sfx[256];
    int t = threadIdx.x;
    unsigned local[16];
    unsigned s = 0;
    #pragma unroll
    for (int j = 0; j < 16; ++j) { local[j] = hist[t * 16 + j]; s += local[j]; }
    sfx[t] = s;
    __syncthreads();
    for (int off = 1; off < 256; off <<= 1) {
        unsigned add = (t + off < 256) ? sfx[t + off] : 0;
        __syncthreads();
        sfx[t] += add;
        __syncthreads();
    }
    unsigned krem = (unsigned)(*kptr);
    unsigned above = (t + 1 < 256) ? sfx[t + 1] : 0;
    if (above < krem && sfx[t] >= krem) {
        unsigned cum = above;
        int b = t * 16;
        for (int j = 15; j >= 0; --j) {
            unsigned cc = local[j];
            if (cum + cc >= krem) { b = t * 16 + j; break; }
            cum += cc;
        }
        sel[0] = krem - cum;            // remaining k within bin b
        sel[1] = ((unsigned)b) << 20;   // 12-bit prefix
    }
}

// ------------- compact candidates with matching 12-bit prefix -------------
__global__ void compact_kernel(const float4* __restrict__ scores4,
                               const unsigned* __restrict__ sel,
                               uint2* __restrict__ cand, unsigned* __restrict__ candCount,
                               int n4, int nnz) {
    unsigned pref = sel[1] >> 20;
    int tid = blockIdx.x * blockDim.x + threadIdx.x;
    int stride = gridDim.x * blockDim.x;
    int lane = threadIdx.x & 63;
    int niter = (n4 + stride - 1) / stride;
    for (int kk = 0; kk < niter; ++kk) {
        int i = tid + kk * stride;
        bool inb = (i < n4);
        float4 sv = make_float4(0.f, 0.f, 0.f, 0.f);
        if (inb) sv = scores4[i];
        unsigned bb[4] = {__float_as_uint(sv.x), __float_as_uint(sv.y),
                          __float_as_uint(sv.z), __float_as_uint(sv.w)};
        #pragma unroll
        for (int q = 0; q < 4; ++q) {
            bool pred = inb && ((bb[q] >> 20) == pref);
            unsigned long long mask = __ballot(pred);
            if (mask) {
                int leader = __ffsll((unsigned long long)mask) - 1;
                unsigned base = 0;
                if (lane == leader) base = atomicAdd(candCount, (unsigned)__popcll(mask));
                base = __shfl(base, leader, 64);
                if (pred) {
                    unsigned rank = __popcll(mask & ((1ull << lane) - 1ull));
                    unsigned pos = base + rank;
                    if (pos < CAND_CAP) cand[pos] = make_uint2(bb[q], (unsigned)(i * 4 + q));
                }
            }
        }
    }
    // scalar tail
    for (int i = n4 * 4 + tid; i < nnz; i += stride) {
        unsigned b = __float_as_uint(((const float*)scores4)[i]);
        if ((b >> 20) == pref) {
            unsigned pos = atomicAdd(candCount, 1u);
            if (pos < CAND_CAP) cand[pos] = make_uint2(b, (unsigned)i);
        }
    }
}

// ------------- single-block selection among candidates: T, m, tie list -------------
__global__ __launch_bounds__(256) void select_small(const uint2* __restrict__ cand,
                            const unsigned* __restrict__ candCount,
                            unsigned* __restrict__ sel, unsigned* __restrict__ tieList) {
    __shared__ unsigned h2[4096];
    __shared__ unsigned sfx[256];
    __shared__ unsigned sB2, sKrem2, sT, sM;
    __shared__ unsigned h3[256];
    __shared__ unsigned ties[TIE_CAP];
    __shared__ unsigned tcnt;
    int t = threadIdx.x;
    unsigned nc = *candCount;
    int n = (nc < CAND_CAP) ? (int)nc : CAND_CAP;
    unsigned krem = sel[0];
    unsigned pref = sel[1];

    for (int j = t; j < 4096; j += 256) h2[j] = 0;
    if (t == 0) tcnt = 0;
    __syncthreads();
    for (int j = t; j < n; j += 256) atomicAdd(&h2[(cand[j].x >> 8) & 0xFFF], 1u);
    __syncthreads();

    // level-2 suffix scan (4096 bins, 16/thread)
    unsigned local[16];
    unsigned s = 0;
    #pragma unroll
    for (int j = 0; j < 16; ++j) { local[j] = h2[t * 16 + j]; s += local[j]; }
    sfx[t] = s;
    __syncthreads();
    for (int off = 1; off < 256; off <<= 1) {
        unsigned add = (t + off < 256) ? sfx[t + off] : 0;
        __syncthreads();
        sfx[t] += add;
        __syncthreads();
    }
    {
        unsigned above = (t + 1 < 256) ? sfx[t + 1] : 0;
        if (above < krem && sfx[t] >= krem) {
            unsigned cum = above;
            int b = t * 16;
            for (int j = 15; j >= 0; --j) {
                unsigned cc = local[j];
                if (cum + cc >= krem) { b = t * 16 + j; break; }
                cum += cc;
            }
            sB2 = (unsigned)b;
            sKrem2 = krem - cum;
        }
    }
    __syncthreads();

    // level-3 histogram (256 bins) among cand matching b2
    h3[t] = 0;
    __syncthreads();
    unsigned b2 = sB2;
    for (int j = t; j < n; j += 256) {
        unsigned x = cand[j].x;
        if (((x >> 8) & 0xFFF) == b2) atomicAdd(&h3[x & 0xFF], 1u);
    }
    __syncthreads();
    sfx[t] = h3[t];
    __syncthreads();
    for (int off = 1; off < 256; off <<= 1) {
        unsigned add = (t + off < 256) ? sfx[t + off] : 0;
        __syncthreads();
        sfx[t] += add;
        __syncthreads();
    }
    {
        unsigned krem2 = sKrem2;
        unsigned above = (t + 1 < 256) ? sfx[t + 1] : 0;
        if (above < krem2 && sfx[t] >= krem2) {
            sT = pref | (b2 << 8) | (unsigned)t;
            sM = krem2 - above;
        }
    }
    __syncthreads();

    // collect tie indices (cand.x == T), sort ascending, keep first m
    unsigned T = sT;
    for (int j = t; j < n; j += 256) {
        if (cand[j].x == T) {
            unsigned p = atomicAdd(&tcnt, 1u);
            if (p < TIE_CAP) ties[p] = cand[j].y;
        }
    }
    __syncthreads();
    if (t == 0) {
        unsigned cnt = (tcnt < TIE_CAP) ? tcnt : TIE_CAP;
        // insertion sort (tie count is tiny in practice)
        for (unsigned a = 1; a < cnt; ++a) {
            unsigned key = ties[a];
            int bpos = (int)a - 1;
            while (bpos >= 0 && ties[bpos] > key) { ties[bpos + 1] = ties[bpos]; --bpos; }
            ties[bpos + 1] = key;
        }
        unsigned m = sM;
        if (m > cnt) m = cnt;
        sel[2] = T;
        sel[3] = m;
        for (unsigned j = 0; j < m; ++j) tieList[j] = ties[j];
    }
}

// ------------- final classification: hard/soft + e_hsum -------------
__global__ __launch_bounds__(256) void write_hard(const float4* __restrict__ scores4,
                           const unsigned* __restrict__ sel,
                           const unsigned* __restrict__ tieList,
                           float4* __restrict__ hard4, float4* __restrict__ soft4,
                           const int4* __restrict__ E4, unsigned* __restrict__ e_hsum,
                           int n4, int nnz) {
    __shared__ unsigned ties[TIE_CAP];
    unsigned T = sel[2];
    unsigned m = sel[3];
    if (m > TIE_CAP) m = TIE_CAP;
    for (int j = threadIdx.x; j < (int)m; j += blockDim.x) ties[j] = tieList[j];
    __syncthreads();
    int tid = blockIdx.x * blockDim.x + threadIdx.x;
    int stride = gridDim.x * blockDim.x;
    for (int i = tid; i < n4; i += stride) {
        float4 sv = scores4[i];
        int4 e = E4[i];
        unsigned bb[4] = {__float_as_uint(sv.x), __float_as_uint(sv.y),
                          __float_as_uint(sv.z), __float_as_uint(sv.w)};
        int ea[4] = {e.x, e.y, e.z, e.w};
        float hv[4];
        #pragma unroll
        for (int q = 0; q < 4; ++q) {
            bool keep = (bb[q] > T);
            if (bb[q] == T) {
                unsigned idx = (unsigned)(i * 4 + q);
                int lo = 0, hi = (int)m - 1;
                bool found = false;
                while (lo <= hi) {
                    int mid = (lo + hi) >> 1;
                    unsigned v = ties[mid];
                    if (v == idx) { found = true; break; }
                    if (v < idx) lo = mid + 1; else hi = mid - 1;
                }
                keep = found;
            }
            hv[q] = keep ? 1.0f : 0.0f;
            if (keep) atomicAdd(&e_hsum[ea[q]], 1u);
        }
        float4 out = make_float4(hv[0], hv[1], hv[2], hv[3]);
        hard4[i] = out;
        soft4[i] = out;
    }
    // scalar tail
    const float* sc = (const float*)scores4;
    const int* Ei = (const int*)E4;
    float* hard = (float*)hard4;
    float* soft = (float*)soft4;
    for (int i = n4 * 4 + tid; i < nnz; i += stride) {
        unsigned b = __float_as_uint(sc[i]);
        bool keep = (b > T);
        if (b == T) {
            unsigned idx = (unsigned)i;
            int lo = 0, hi = (int)m - 1;
            bool found = false;
            while (lo <= hi) {
                int mid = (lo + hi) >> 1;
                unsigned v = ties[mid];
                if (v == idx) { found = true; break; }
                if (v < idx) lo = mid + 1; else hi = mid - 1;
            }
            keep = found;
        }
        float hvv = keep ? 1.0f : 0.0f;
        hard[i] = hvv;
        soft[i] = hvv;
        if (keep) atomicAdd(&e_hsum[Ei[i]], 1u);
    }
}

// ---------------- per-hyperedge finalize ----------------
__global__ void finalize_edges(const float* __restrict__ ssum, const unsigned* __restrict__ cnt,
                               const unsigned* __restrict__ hsum,
                               float* __restrict__ eprob, float* __restrict__ esoft,
                               float* __restrict__ ehard, int nhe) {
    int j = blockIdx.x * blockDim.x + threadIdx.x;
    if (j >= nhe) return;
    float c = fmaxf((float)cnt[j], 1.0f);
    eprob[j] = ssum[j] / c;
    esoft[j] = (float)hsum[j] / c;
    ehard[j] = (hsum[j] > 0) ? 1.0f : 0.0f;
}

extern "C" void kernel_launch(void* const* d_in, const int* in_sizes, int n_in,
                              void* d_out, int out_size, void* d_ws, size_t ws_size,
                              hipStream_t stream) {
    const float* x        = (const float*)d_in[0];
    const float* Wm       = (const float*)d_in[1];
    const float* ef       = (const float*)d_in[2];
    const int*   V_idx    = (const int*)d_in[3];
    const int*   E_idx    = (const int*)d_in[4];
    const int*   edge_ids = (const int*)d_in[5];
    const int*   kptr     = (const int*)d_in[6];

    const int nnz     = in_sizes[3];
    const int nhe     = in_sizes[5];
    const int n_nodes = in_sizes[0] / FEAT;

    float* out    = (float*)d_out;
    float* scores = out;
    float* soft   = out + (size_t)nnz;
    float* hard   = out + 2 * (size_t)nnz;
    float* eprob  = out + 3 * (size_t)nnz;
    float* esoft  = eprob + nhe;
    float* ehard  = esoft + nhe;

    // ---- aux zone (always in d_ws) ----
    char* w = (char*)d_ws;
    float*    e_ssum    = (float*)w;
    unsigned* e_cnt     = (unsigned*)(e_ssum + nhe);
    unsigned* e_hsum    = e_cnt + nhe;
    unsigned* hist1     = e_hsum + nhe;
    unsigned* candCount = hist1 + 4096;
    unsigned* sel       = candCount + 1;      // 8 slots
    unsigned* tieList   = sel + 8;            // TIE_CAP slots
    char* auxEnd = (char*)(tieList + TIE_CAP);
    size_t memsetBytes = (size_t)((char*)(candCount + 1) - (char*)w);
    size_t auxAligned = (((size_t)(auxEnd - w)) + 255) & ~(size_t)255;

    size_t ef2Bytes  = (size_t)nhe * RANKK * sizeof(float);
    size_t projBytes = (size_t)n_nodes * RANKK * sizeof(float);
    size_t candBytes = (size_t)CAND_CAP * sizeof(uint2);

    // big buffers: prefer ws, fall back into not-yet-written output regions
    float* ef2;
    float* proj;
    uint2* cand;
    size_t off = auxAligned;
    if (ws_size >= off + ef2Bytes + projBytes) {
        ef2  = (float*)(w + off);
        proj = (float*)(w + off + ef2Bytes);
        off += ef2Bytes + projBytes;
    } else {
        // soft region: consumed by score_kernel before write_hard overwrites it
        ef2  = soft;
        proj = soft + (size_t)nhe * RANKK;
    }
    if (ws_size >= off + candBytes) {
        cand = (uint2*)(w + off);
    } else {
        // hard region: written only by write_hard, after cand is consumed
        cand = (uint2*)hard;
    }

    hipMemsetAsync(w, 0, memsetBytes, stream);

    gather_ef<<<(nhe * 4 + 255) / 256, 256, 0, stream>>>(
        (const float4*)ef, edge_ids, (float4*)ef2, nhe);
    proj_kernel<<<(n_nodes + PRJ_NODES - 1) / PRJ_NODES, 256, 0, stream>>>(
        x, Wm, proj, n_nodes);

    score_kernel<<<2048, 256, 0, stream>>>(
        (const float4*)proj, (const float4*)ef2, V_idx, E_idx,
        scores, e_ssum, e_cnt, hist1, nnz);

    int n4 = nnz / 4;
    scan1_kernel<<<1, 256, 0, stream>>>(hist1, sel, kptr);
    compact_kernel<<<1024, 256, 0, stream>>>(
        (const float4*)scores, sel, cand, candCount, n4, nnz);
    select_small<<<1, 256, 0, stream>>>(cand, candCount, sel, tieList);
    write_hard<<<1024, 256, 0, stream>>>(
        (const float4*)scores, sel, tieList, (float4*)hard, (float4*)soft,
        (const int4*)E_idx, e_hsum, n4, nnz);
    finalize_edges<<<(nhe + 255) / 256, 256, 0, stream>>>(e_ssum, e_cnt, e_hsum,
                                                          eprob, esoft, ehard, nhe);
}

// Round 4
// 525.629 us; speedup vs baseline: 2.5107x; 1.2709x over previous
//
#include <hip/hip_runtime.h>
#include <math.h>

#define FEAT 256
#define RANKK 16
#define PRJ_NODES 16
#define CAND_CAP 131072
#define TIE_CAP 2048
#define NBK_MAX 512   // max buckets (nhe/256)

typedef unsigned long long u64;

static __device__ __forceinline__ u64 pack_pair(unsigned e_low, unsigned bits, unsigned idx) {
    // [63:56]=e&255, [55:26]=score bits (<2^30 since score<=1.0f), [25:0]=idx
    return ((u64)e_low << 56) | ((u64)bits << 26) | (u64)idx;
}

// ---------------- proj = x @ W^T  (double accumulation, f32 output) ----------------
__global__ __launch_bounds__(256) void proj_kernel(const float* __restrict__ x,
        const float* __restrict__ Wm, float* __restrict__ proj, int n_nodes) {
    __shared__ float Ws[RANKK][FEAT + 4];
    __shared__ float Xs[PRJ_NODES][FEAT + 4];
    const float4* x4 = (const float4*)x;
    const float4* w4 = (const float4*)Wm;
    for (int t = threadIdx.x; t < RANKK * (FEAT / 4); t += 256) {
        int r = t >> 6, j4 = t & 63;
        *(float4*)&Ws[r][j4 * 4] = w4[t];
    }
    int nodeBase = blockIdx.x * PRJ_NODES;
    for (int t = threadIdx.x; t < PRJ_NODES * (FEAT / 4); t += 256) {
        int n = t >> 6, j4 = t & 63;
        int node = nodeBase + n;
        float4 v = make_float4(0.f, 0.f, 0.f, 0.f);
        if (node < n_nodes) v = x4[(size_t)node * (FEAT / 4) + j4];
        *(float4*)&Xs[n][j4 * 4] = v;
    }
    __syncthreads();
    int n = threadIdx.x >> 4, r = threadIdx.x & 15;
    int node = nodeBase + n;
    if (node >= n_nodes) return;
    double acc = 0.0;
    #pragma unroll 8
    for (int j4 = 0; j4 < FEAT / 4; ++j4) {
        float4 xv = *(const float4*)&Xs[n][j4 * 4];
        float4 wv = *(const float4*)&Ws[r][j4 * 4];
        acc += (double)xv.x * (double)wv.x + (double)xv.y * (double)wv.y
             + (double)xv.z * (double)wv.z + (double)xv.w * (double)wv.w;
    }
    proj[(size_t)node * RANKK + r] = (float)acc;
}

// ---------------- ef2[e] = ef[edge_ids[e]] ----------------
__global__ void gather_ef(const float4* __restrict__ ef, const int* __restrict__ edge_ids,
                          float4* __restrict__ ef2, int nhe) {
    int t = blockIdx.x * blockDim.x + threadIdx.x;
    if (t >= nhe * 4) return;
    int e = t >> 2, c = t & 3;
    ef2[(size_t)e * 4 + c] = ef[(size_t)edge_ids[e] * 4 + c];
}

// ---------------- bucket histogram of E_idx>>8 ----------------
__global__ void ehist_kernel(const int* __restrict__ E_idx, unsigned* __restrict__ bucketCnt,
                             int nnz, int nb) {
    __shared__ unsigned h[NBK_MAX];
    for (int t = threadIdx.x; t < NBK_MAX; t += blockDim.x) h[t] = 0;
    __syncthreads();
    for (int i = blockIdx.x * blockDim.x + threadIdx.x; i < nnz; i += gridDim.x * blockDim.x)
        atomicAdd(&h[((unsigned)E_idx[i]) >> 8], 1u);
    __syncthreads();
    for (int t = threadIdx.x; t < nb; t += blockDim.x)
        if (h[t]) atomicAdd(&bucketCnt[t], h[t]);
}

// ---------------- exclusive scan over bucket counts ----------------
__global__ void bucket_scan(const unsigned* __restrict__ bucketCnt,
                            unsigned* __restrict__ bucketBase, unsigned* __restrict__ cursor,
                            int nb, int nnz) {
    __shared__ unsigned s[NBK_MAX];
    int t = threadIdx.x;  // NBK_MAX threads
    unsigned c = (t < nb) ? bucketCnt[t] : 0u;
    s[t] = c;
    __syncthreads();
    for (int off = 1; off < NBK_MAX; off <<= 1) {
        unsigned v = (t >= off) ? s[t - off] : 0u;
        __syncthreads();
        s[t] += v;
        __syncthreads();
    }
    unsigned excl = s[t] - c;
    if (t < nb) { bucketBase[t] = excl; cursor[t] = excl; }
    if (t == 0) bucketBase[nb] = (unsigned)nnz;
}

// ---------------- pure score kernel: gather, f64 dot, sigmoid, store ----------------
__global__ __launch_bounds__(256) void score_kernel(
        const float4* __restrict__ proj4, const float4* __restrict__ ef4,
        const int* __restrict__ V_idx, const int* __restrict__ E_idx,
        float* __restrict__ scores, int nnz) {
    int stride = gridDim.x * blockDim.x;
    #pragma unroll 2
    for (int i = blockIdx.x * blockDim.x + threadIdx.x; i < nnz; i += stride) {
        int v = V_idx[i], e = E_idx[i];
        float4 p0 = proj4[(size_t)v * 4 + 0];
        float4 p1 = proj4[(size_t)v * 4 + 1];
        float4 p2 = proj4[(size_t)v * 4 + 2];
        float4 p3 = proj4[(size_t)v * 4 + 3];
        float4 f0 = ef4[(size_t)e * 4 + 0];
        float4 f1 = ef4[(size_t)e * 4 + 1];
        float4 f2 = ef4[(size_t)e * 4 + 2];
        float4 f3 = ef4[(size_t)e * 4 + 3];
        double acc = (double)p0.x * f0.x + (double)p0.y * f0.y + (double)p0.z * f0.z + (double)p0.w * f0.w
                   + (double)p1.x * f1.x + (double)p1.y * f1.y + (double)p1.z * f1.z + (double)p1.w * f1.w
                   + (double)p2.x * f2.x + (double)p2.y * f2.y + (double)p2.z * f2.z + (double)p2.w * f2.w
                   + (double)p3.x * f3.x + (double)p3.y * f3.y + (double)p3.z * f3.z + (double)p3.w * f3.w;
        scores[i] = (float)(1.0 / (1.0 + exp(-acc)));
    }
}

// ---------------- level-1 histogram over scores (hot bins pre-counted) ----------------
__global__ void hist1_kernel(const float4* __restrict__ scores4, unsigned* __restrict__ hist1g,
                             int n4, int nnz) {
    __shared__ unsigned h[4096];
    for (int t = threadIdx.x; t < 4096; t += blockDim.x) h[t] = 0;
    __syncthreads();
    unsigned r1016 = 0, r1015 = 0, r0 = 0;
    int stride = gridDim.x * blockDim.x;
    for (int i = blockIdx.x * blockDim.x + threadIdx.x; i < n4; i += stride) {
        float4 sv = scores4[i];
        unsigned bb[4] = {__float_as_uint(sv.x), __float_as_uint(sv.y),
                          __float_as_uint(sv.z), __float_as_uint(sv.w)};
        #pragma unroll
        for (int q = 0; q < 4; ++q) {
            unsigned b = bb[q] >> 20;
            if (b == 1016) ++r1016;
            else if (b == 1015) ++r1015;
            else if (b == 0) ++r0;
            else atomicAdd(&h[b], 1u);
        }
    }
    for (int i = n4 * 4 + blockIdx.x * blockDim.x + threadIdx.x; i < nnz; i += stride) {
        unsigned b = __float_as_uint(((const float*)scores4)[i]) >> 20;
        if (b == 1016) ++r1016;
        else if (b == 1015) ++r1015;
        else if (b == 0) ++r0;
        else atomicAdd(&h[b], 1u);
    }
    if (r1016) atomicAdd(&h[1016], r1016);
    if (r1015) atomicAdd(&h[1015], r1015);
    if (r0) atomicAdd(&h[0], r0);
    __syncthreads();
    for (int t = threadIdx.x; t < 4096; t += blockDim.x)
        if (h[t]) atomicAdd(&hist1g[t], h[t]);
}

// ---------------- build bucket-ordered pairs (block-aggregated allocation) ----------------
#define PB_CHUNK 8192
__global__ __launch_bounds__(256) void pair_build(const int* __restrict__ E_idx,
        const float* __restrict__ scores, u64* __restrict__ pairs,
        unsigned* __restrict__ cursor, int nnz, int nb) {
    __shared__ unsigned bh[NBK_MAX];
    for (int t = threadIdx.x; t < NBK_MAX; t += 256) bh[t] = 0;
    __syncthreads();
    int base = blockIdx.x * PB_CHUNK;
    int nE = nnz - base;
    if (nE > PB_CHUNK) nE = PB_CHUNK;
    for (int o = threadIdx.x; o < nE; o += 256)
        atomicAdd(&bh[((unsigned)E_idx[base + o]) >> 8], 1u);
    __syncthreads();
    for (int b = threadIdx.x; b < nb; b += 256) {
        unsigned c = bh[b];
        bh[b] = c ? atomicAdd(&cursor[b], c) : 0u;
    }
    __syncthreads();
    for (int o = threadIdx.x; o < nE; o += 256) {
        int i = base + o;
        unsigned e = (unsigned)E_idx[i];
        unsigned bits = __float_as_uint(scores[i]);
        unsigned pos = atomicAdd(&bh[e >> 8], 1u);
        pairs[pos] = pack_pair(e & 255u, bits, (unsigned)i);
    }
}

// ---------------- parallel level-1 suffix scan (1 block) ----------------
__global__ void scan1_kernel(const unsigned* __restrict__ hist,
                             unsigned* __restrict__ sel, const int* __restrict__ kptr) {
    __shared__ unsigned sfx[256];
    int t = threadIdx.x;
    unsigned local[16];
    unsigned s = 0;
    #pragma unroll
    for (int j = 0; j < 16; ++j) { local[j] = hist[t * 16 + j]; s += local[j]; }
    sfx[t] = s;
    __syncthreads();
    for (int off = 1; off < 256; off <<= 1) {
        unsigned add = (t + off < 256) ? sfx[t + off] : 0;
        __syncthreads();
        sfx[t] += add;
        __syncthreads();
    }
    unsigned krem = (unsigned)(*kptr);
    unsigned above = (t + 1 < 256) ? sfx[t + 1] : 0;
    if (above < krem && sfx[t] >= krem) {
        unsigned cum = above;
        int b = t * 16;
        for (int j = 15; j >= 0; --j) {
            unsigned cc = local[j];
            if (cum + cc >= krem) { b = t * 16 + j; break; }
            cum += cc;
        }
        sel[0] = krem - cum;            // remaining k within bin b
        sel[1] = ((unsigned)b) << 20;   // 12-bit prefix
    }
}

// ---------------- compact candidates (from pairs) ----------------
__global__ void compact_kernel(const u64* __restrict__ pairs, const unsigned* __restrict__ sel,
                               uint2* __restrict__ cand, unsigned* __restrict__ candCount, int nnz) {
    unsigned pref = sel[1] >> 20;
    int tid = blockIdx.x * blockDim.x + threadIdx.x;
    int stride = gridDim.x * blockDim.x;
    int lane = threadIdx.x & 63;
    for (int i = tid; i < nnz; i += stride) {
        u64 p = pairs[i];
        unsigned bits = (unsigned)(p >> 26) & 0x3FFFFFFFu;
        bool pred = (bits >> 20) == pref;
        unsigned long long mask = __ballot(pred);
        if (mask) {
            int leader = __ffsll(mask) - 1;
            unsigned base = 0;
            if (lane == leader) base = atomicAdd(candCount, (unsigned)__popcll(mask));
            base = __shfl(base, leader, 64);
            if (pred) {
                unsigned rank = __popcll(mask & ((1ull << lane) - 1ull));
                unsigned pos = base + rank;
                if (pos < CAND_CAP) cand[pos] = make_uint2(bits, (unsigned)(p & 0x3FFFFFFu));
            }
        }
    }
}

// ---------------- single-block selection among candidates ----------------
__global__ __launch_bounds__(256) void select_small(const uint2* __restrict__ cand,
                            const unsigned* __restrict__ candCount,
                            unsigned* __restrict__ sel, unsigned* __restrict__ tieList) {
    __shared__ unsigned h2[4096];
    __shared__ unsigned sfx[256];
    __shared__ unsigned sB2, sKrem2, sT, sM;
    __shared__ unsigned h3[256];
    __shared__ unsigned ties[TIE_CAP];
    __shared__ unsigned tcnt;
    int t = threadIdx.x;
    unsigned nc = *candCount;
    int n = (nc < CAND_CAP) ? (int)nc : CAND_CAP;
    unsigned krem = sel[0];
    unsigned pref = sel[1];

    for (int j = t; j < 4096; j += 256) h2[j] = 0;
    if (t == 0) tcnt = 0;
    __syncthreads();
    for (int j = t; j < n; j += 256) atomicAdd(&h2[(cand[j].x >> 8) & 0xFFF], 1u);
    __syncthreads();

    unsigned local[16];
    unsigned s = 0;
    #pragma unroll
    for (int j = 0; j < 16; ++j) { local[j] = h2[t * 16 + j]; s += local[j]; }
    sfx[t] = s;
    __syncthreads();
    for (int off = 1; off < 256; off <<= 1) {
        unsigned add = (t + off < 256) ? sfx[t + off] : 0;
        __syncthreads();
        sfx[t] += add;
        __syncthreads();
    }
    {
        unsigned above = (t + 1 < 256) ? sfx[t + 1] : 0;
        if (above < krem && sfx[t] >= krem) {
            unsigned cum = above;
            int b = t * 16;
            for (int j = 15; j >= 0; --j) {
                unsigned cc = local[j];
                if (cum + cc >= krem) { b = t * 16 + j; break; }
                cum += cc;
            }
            sB2 = (unsigned)b;
            sKrem2 = krem - cum;
        }
    }
    __syncthreads();

    h3[t] = 0;
    __syncthreads();
    unsigned b2 = sB2;
    for (int j = t; j < n; j += 256) {
        unsigned x = cand[j].x;
        if (((x >> 8) & 0xFFF) == b2) atomicAdd(&h3[x & 0xFF], 1u);
    }
    __syncthreads();
    sfx[t] = h3[t];
    __syncthreads();
    for (int off = 1; off < 256; off <<= 1) {
        unsigned add = (t + off < 256) ? sfx[t + off] : 0;
        __syncthreads();
        sfx[t] += add;
        __syncthreads();
    }
    {
        unsigned krem2 = sKrem2;
        unsigned above = (t + 1 < 256) ? sfx[t + 1] : 0;
        if (above < krem2 && sfx[t] >= krem2) {
            sT = pref | (b2 << 8) | (unsigned)t;
            sM = krem2 - above;
        }
    }
    __syncthreads();

    unsigned T = sT;
    for (int j = t; j < n; j += 256) {
        if (cand[j].x == T) {
            unsigned p = atomicAdd(&tcnt, 1u);
            if (p < TIE_CAP) ties[p] = cand[j].y;
        }
    }
    __syncthreads();
    if (t == 0) {
        unsigned cnt = (tcnt < TIE_CAP) ? tcnt : TIE_CAP;
        for (unsigned a = 1; a < cnt; ++a) {
            unsigned key = ties[a];
            int bpos = (int)a - 1;
            while (bpos >= 0 && ties[bpos] > key) { ties[bpos + 1] = ties[bpos]; --bpos; }
            ties[bpos + 1] = key;
        }
        unsigned m = sM;
        if (m > cnt) m = cnt;
        sel[2] = T;
        sel[3] = m;
        for (unsigned j = 0; j < m; ++j) tieList[j] = ties[j];
    }
}

// ---------------- per-bucket e_ssum / e_cnt (no global atomics) ----------------
__global__ __launch_bounds__(256) void esum_kernel(const u64* __restrict__ pairs,
        const unsigned* __restrict__ bucketBase,
        float* __restrict__ e_ssum, unsigned* __restrict__ e_cnt, int nhe) {
    __shared__ float ss[256];
    __shared__ unsigned cc[256];
    int t = threadIdx.x, b = blockIdx.x;
    ss[t] = 0.f; cc[t] = 0u;
    __syncthreads();
    unsigned n0 = bucketBase[b], n1 = bucketBase[b + 1];
    for (unsigned j = n0 + t; j < n1; j += 256) {
        u64 p = pairs[j];
        unsigned el = (unsigned)(p >> 56);
        unsigned bits = (unsigned)(p >> 26) & 0x3FFFFFFFu;
        atomicAdd(&ss[el], __uint_as_float(bits));
        atomicAdd(&cc[el], 1u);
    }
    __syncthreads();
    int e = b * 256 + t;
    if (e < nhe) { e_ssum[e] = ss[t]; e_cnt[e] = cc[t]; }
}

// ---------------- per-bucket e_hsum (no global atomics) ----------------
__global__ __launch_bounds__(256) void ehard_kernel(const u64* __restrict__ pairs,
        const unsigned* __restrict__ bucketBase, const unsigned* __restrict__ sel,
        const unsigned* __restrict__ tieList, unsigned* __restrict__ e_hsum, int nhe) {
    __shared__ unsigned hh[256];
    __shared__ unsigned ties[TIE_CAP];
    unsigned T = sel[2];
    unsigned m = sel[3];
    if (m > TIE_CAP) m = TIE_CAP;
    hh[threadIdx.x] = 0;
    for (int j = threadIdx.x; j < (int)m; j += 256) ties[j] = tieList[j];
    __syncthreads();
    int b = blockIdx.x;
    unsigned n0 = bucketBase[b], n1 = bucketBase[b + 1];
    for (unsigned j = n0 + threadIdx.x; j < n1; j += 256) {
        u64 p = pairs[j];
        unsigned bits = (unsigned)(p >> 26) & 0x3FFFFFFFu;
        bool keep = bits > T;
        if (bits == T) {
            unsigned idx = (unsigned)(p & 0x3FFFFFFu);
            int lo = 0, hi = (int)m - 1;
            keep = false;
            while (lo <= hi) {
                int mid = (lo + hi) >> 1;
                unsigned v = ties[mid];
                if (v == idx) { keep = true; break; }
                if (v < idx) lo = mid + 1; else hi = mid - 1;
            }
        }
        if (keep) atomicAdd(&hh[(unsigned)(p >> 56)], 1u);
    }
    __syncthreads();
    int e = b * 256 + threadIdx.x;
    if (e < nhe) e_hsum[e] = hh[threadIdx.x];
}

// ---------------- final classification: hard/soft (coalesced, no atomics) ----------------
__global__ __launch_bounds__(256) void write_hard(const float4* __restrict__ scores4,
                           const unsigned* __restrict__ sel,
                           const unsigned* __restrict__ tieList,
                           float4* __restrict__ hard4, float4* __restrict__ soft4,
                           int n4, int nnz) {
    __shared__ unsigned ties[TIE_CAP];
    unsigned T = sel[2];
    unsigned m = sel[3];
    if (m > TIE_CAP) m = TIE_CAP;
    for (int j = threadIdx.x; j < (int)m; j += blockDim.x) ties[j] = tieList[j];
    __syncthreads();
    int tid = blockIdx.x * blockDim.x + threadIdx.x;
    int stride = gridDim.x * blockDim.x;
    for (int i = tid; i < n4; i += stride) {
        float4 sv = scores4[i];
        unsigned bb[4] = {__float_as_uint(sv.x), __float_as_uint(sv.y),
                          __float_as_uint(sv.z), __float_as_uint(sv.w)};
        float hv[4];
        #pragma unroll
        for (int q = 0; q < 4; ++q) {
            bool keep = (bb[q] > T);
            if (bb[q] == T) {
                unsigned idx = (unsigned)(i * 4 + q);
                int lo = 0, hi = (int)m - 1;
                keep = false;
                while (lo <= hi) {
                    int mid = (lo + hi) >> 1;
                    unsigned v = ties[mid];
                    if (v == idx) { keep = true; break; }
                    if (v < idx) lo = mid + 1; else hi = mid - 1;
                }
            }
            hv[q] = keep ? 1.0f : 0.0f;
        }
        float4 outv = make_float4(hv[0], hv[1], hv[2], hv[3]);
        hard4[i] = outv;
        soft4[i] = outv;
    }
    const float* sc = (const float*)scores4;
    float* hard = (float*)hard4;
    float* soft = (float*)soft4;
    for (int i = n4 * 4 + tid; i < nnz; i += stride) {
        unsigned b = __float_as_uint(sc[i]);
        bool keep = (b > T);
        if (b == T) {
            unsigned idx = (unsigned)i;
            int lo = 0, hi = (int)m - 1;
            keep = false;
            while (lo <= hi) {
                int mid = (lo + hi) >> 1;
                unsigned v = ties[mid];
                if (v == idx) { keep = true; break; }
                if (v < idx) lo = mid + 1; else hi = mid - 1;
            }
        }
        float hvv = keep ? 1.0f : 0.0f;
        hard[i] = hvv;
        soft[i] = hvv;
    }
}

// ---------------- per-hyperedge finalize ----------------
__global__ void finalize_edges(const float* __restrict__ ssum, const unsigned* __restrict__ cnt,
                               const unsigned* __restrict__ hsum,
                               float* __restrict__ eprob, float* __restrict__ esoft,
                               float* __restrict__ ehard, int nhe) {
    int j = blockIdx.x * blockDim.x + threadIdx.x;
    if (j >= nhe) return;
    float c = fmaxf((float)cnt[j], 1.0f);
    eprob[j] = ssum[j] / c;
    esoft[j] = (float)hsum[j] / c;
    ehard[j] = (hsum[j] > 0) ? 1.0f : 0.0f;
}

extern "C" void kernel_launch(void* const* d_in, const int* in_sizes, int n_in,
                              void* d_out, int out_size, void* d_ws, size_t ws_size,
                              hipStream_t stream) {
    const float* x        = (const float*)d_in[0];
    const float* Wm       = (const float*)d_in[1];
    const float* ef       = (const float*)d_in[2];
    const int*   V_idx    = (const int*)d_in[3];
    const int*   E_idx    = (const int*)d_in[4];
    const int*   edge_ids = (const int*)d_in[5];
    const int*   kptr     = (const int*)d_in[6];

    const int nnz     = in_sizes[3];
    const int nhe     = in_sizes[5];
    const int n_nodes = in_sizes[0] / FEAT;
    const int nb      = (nhe + 255) >> 8;   // buckets of 256 edges (<= NBK_MAX)

    float* out    = (float*)d_out;
    float* scores = out;
    float* soft   = out + (size_t)nnz;
    float* hard   = out + 2 * (size_t)nnz;
    float* eprob  = out + 3 * (size_t)nnz;
    float* esoft  = eprob + nhe;
    float* ehard  = esoft + nhe;

    // pairs live in soft+hard (exactly nnz u64); consumed before write_hard.
    u64*   pairs = (u64*)soft;
    // cand lives in eprob+esoft+ehard (1 MB <= 1.43 MB); consumed before finalize.
    uint2* cand  = (uint2*)eprob;

    // ---- aux zone in d_ws ----
    char* w = (char*)d_ws;
    unsigned* hist1      = (unsigned*)w;               // 4096
    unsigned* bucketCnt  = hist1 + 4096;               // NBK_MAX
    unsigned* candCount  = bucketCnt + NBK_MAX;        // 1
    unsigned* sel        = candCount + 1;              // 8
    unsigned* tieList    = sel + 8;                    // TIE_CAP
    unsigned* bucketBase = tieList + TIE_CAP;          // NBK_MAX+1
    unsigned* cursor     = bucketBase + NBK_MAX + 1;   // NBK_MAX
    float*    e_ssum     = (float*)(cursor + NBK_MAX);
    unsigned* e_cnt      = (unsigned*)(e_ssum + nhe);
    unsigned* e_hsum     = e_cnt + nhe;
    char* auxEnd = (char*)(e_hsum + nhe);
    size_t auxAligned = (((size_t)(auxEnd - w)) + 255) & ~(size_t)255;

    size_t ef2Bytes  = (size_t)nhe * RANKK * sizeof(float);
    size_t projBytes = (size_t)n_nodes * RANKK * sizeof(float);

    float* ef2;
    float* proj;
    if (ws_size >= auxAligned + ef2Bytes + projBytes) {
        ef2  = (float*)(w + auxAligned);
        proj = (float*)(w + auxAligned + ef2Bytes);
    } else {
        // hard region (nnz floats >= ef2+proj): consumed by score_kernel,
        // which runs before pair_build/write_hard touch hard.
        ef2  = hard;
        proj = hard + (size_t)nhe * RANKK;
    }

    // zero hist1 + bucketCnt + candCount (contiguous)
    hipMemsetAsync(w, 0, (size_t)(4096 + NBK_MAX + 1) * sizeof(unsigned), stream);

    ehist_kernel<<<128, 256, 0, stream>>>(E_idx, bucketCnt, nnz, nb);
    bucket_scan<<<1, NBK_MAX, 0, stream>>>(bucketCnt, bucketBase, cursor, nb, nnz);
    gather_ef<<<(nhe * 4 + 255) / 256, 256, 0, stream>>>(
        (const float4*)ef, edge_ids, (float4*)ef2, nhe);
    proj_kernel<<<(n_nodes + PRJ_NODES - 1) / PRJ_NODES, 256, 0, stream>>>(x, Wm, proj, n_nodes);

    score_kernel<<<2048, 256, 0, stream>>>(
        (const float4*)proj, (const float4*)ef2, V_idx, E_idx, scores, nnz);

    int n4 = nnz / 4;
    hist1_kernel<<<128, 256, 0, stream>>>((const float4*)scores, hist1, n4, nnz);
    pair_build<<<(nnz + PB_CHUNK - 1) / PB_CHUNK, 256, 0, stream>>>(
        E_idx, scores, pairs, cursor, nnz, nb);

    scan1_kernel<<<1, 256, 0, stream>>>(hist1, sel, kptr);
    compact_kernel<<<1024, 256, 0, stream>>>(pairs, sel, cand, candCount, nnz);
    select_small<<<1, 256, 0, stream>>>(cand, candCount, sel, tieList);

    esum_kernel<<<nb, 256, 0, stream>>>(pairs, bucketBase, e_ssum, e_cnt, nhe);
    ehard_kernel<<<nb, 256, 0, stream>>>(pairs, bucketBase, sel, tieList, e_hsum, nhe);

    write_hard<<<1024, 256, 0, stream>>>(
        (const float4*)scores, sel, tieList, (float4*)hard, (float4*)soft, n4, nnz);
    finalize_edges<<<(nhe + 255) / 256, 256, 0, stream>>>(e_ssum, e_cnt, e_hsum,
                                                          eprob, esoft, ehard, nhe);
}